// Round 7
// baseline (197.378 us; speedup 1.0000x reference)
//
#include <hip/hip_runtime.h>

#define HD 64      // hidden/feature dim (D == H == 64)
#define PSUB 16    // partial slots per graph (pool accumulation spread)
#define NBLK 256   // histogram blocks (edge slices)
#define NBKT 512   // dst buckets (bucket = dst >> 7, 128 nodes each; N <= 65536)

// ---- bf16 helpers (manual, RNE) ----
__device__ __forceinline__ unsigned short f2bf(float f) {
    union { float f; unsigned u; } v; v.f = f;
    unsigned r = v.u + 0x7FFF + ((v.u >> 16) & 1);
    return (unsigned short)(r >> 16);
}
__device__ __forceinline__ float u2f(unsigned u) {
    union { unsigned u; float f; } v; v.u = u;
    return v.f;
}

// ================= atomic-free bucketed CSR build (3 kernels) =================

// 1) per-block bucket histogram (BUCKET-MAJOR out: hist[b*NBLK + blk]);
//    also zeroes pool 'partial'; block 0 computes gstart (independent work).
__global__ __launch_bounds__(256) void hist1_k(const int* __restrict__ dst,
    int* __restrict__ hist, int E, int chunk,
    float* __restrict__ partial, int psz,
    const int* __restrict__ batch, int* __restrict__ gstart, int n, int G)
{
    __shared__ int lh[NBKT];
    int t = threadIdx.x;
    for (int i = t; i < NBKT; i += 256) lh[i] = 0;
    for (int i = blockIdx.x * 256 + t; i < psz; i += gridDim.x * 256)
        partial[i] = 0.f;
    if (blockIdx.x == 0 && t <= G) {
        if (t == G) gstart[t] = n;
        else {
            int lo = 0, hi = n;
            while (lo < hi) { int m = (lo + hi) >> 1; if (batch[m] < t) lo = m + 1; else hi = m; }
            gstart[t] = lo;
        }
    }
    __syncthreads();
    int base = blockIdx.x * chunk;
    int end  = min(base + chunk, E);
    for (int i = base + t; i < end; i += 256)
        atomicAdd(&lh[dst[i] >> 7], 1);
    __syncthreads();
    for (int i = t; i < NBKT; i += 256)
        hist[i * NBLK + blockIdx.x] = lh[i];
}

// 2) append with in-block redundant prefix: block k computes
//    start[b] = bucketBase[b] + sum_{k'<k} hist[b][k']  (== old scanned[b*NBLK+k]).
//    Block 0 publishes bucketBase[0..NBKT] for bucket_csr_k.
__global__ __launch_bounds__(256) void append2_k(const int* __restrict__ src,
    const int* __restrict__ dst, const int* __restrict__ hist,
    int* __restrict__ pairs, int* __restrict__ bucketb, int E, int chunk)
{
    __shared__ int cur[NBKT];   // below-count, then absolute start
    __shared__ int tot[NBKT];   // bucket totals
    __shared__ int ps[256];     // pair-scan scratch
    int t = threadIdx.x;
    int k = blockIdx.x;

    // per-thread: buckets b = t and t+256; row-major walk of hist[b][*]
    for (int b = t; b < NBKT; b += 256) {
        const int4* row4 = (const int4*)(hist + b * NBLK);
        int below = 0, total = 0;
        #pragma unroll 4
        for (int c = 0; c < NBLK / 4; ++c) {
            int4 h = row4[c];
            int k0 = c * 4;
            total += h.x + h.y + h.z + h.w;
            below += ((k0 + 0) < k ? h.x : 0) + ((k0 + 1) < k ? h.y : 0)
                   + ((k0 + 2) < k ? h.z : 0) + ((k0 + 3) < k ? h.w : 0);
        }
        tot[b] = total;
        cur[b] = below;
    }
    __syncthreads();

    // exclusive scan of tot[0..511]: thread t owns pair (2t, 2t+1)
    int pa = tot[2 * t], pb = tot[2 * t + 1];
    ps[t] = pa + pb;
    __syncthreads();
    for (int off = 1; off < 256; off <<= 1) {
        int u = (t >= off) ? ps[t - off] : 0;
        __syncthreads();
        ps[t] += u;
        __syncthreads();
    }
    int excl  = ps[t] - (pa + pb);       // exclusive prefix of pair t
    int base0 = excl;
    int base1 = excl + pa;
    cur[2 * t]     += base0;
    cur[2 * t + 1] += base1;
    if (k == 0) {
        bucketb[2 * t]     = base0;
        bucketb[2 * t + 1] = base1;
        if (t == 0) bucketb[NBKT] = E;
    }
    __syncthreads();

    // append this block's edge slice into per-bucket private ranges
    int base = k * chunk;
    int end  = min(base + chunk, E);
    for (int i = base + t; i < end; i += 256) {
        int s = src[i], d = dst[i];
        int p = atomicAdd(&cur[d >> 7], 1);
        pairs[p] = (s << 7) | (d & 127);
    }
}

// 3) per-bucket: node counts -> offsets/dis, then in-bucket scatter of csr_src
__global__ __launch_bounds__(256) void bucket_csr_k(const int* __restrict__ pairs,
    const int* __restrict__ bucketb, int* __restrict__ offsets,
    float* __restrict__ dis, int* __restrict__ csr_src, int N, int E)
{
    __shared__ int cnt[128];
    __shared__ int sc[128];
    __shared__ int cur[128];
    int t = threadIdx.x;
    int b = blockIdx.x;
    int nodeBase = b * 128;
    int nNodes = min(128, N - nodeBase);
    int bBase = bucketb[b];
    int bEnd  = bucketb[b + 1];

    if (t < 128) cnt[t] = 0;
    __syncthreads();
    for (int i = bBase + t; i < bEnd; i += 256)
        atomicAdd(&cnt[pairs[i] & 127], 1);
    __syncthreads();
    int myc = (t < 128) ? cnt[t] : 0;
    if (t < 128) sc[t] = myc;
    __syncthreads();
    for (int off = 1; off < 128; off <<= 1) {
        int u = (t < 128 && t >= off) ? sc[t - off] : 0;
        __syncthreads();
        if (t < 128) sc[t] += u;
        __syncthreads();
    }
    if (t < 128) {
        int excl = sc[t] - myc;
        cur[t] = excl;
        if (t < nNodes) {
            offsets[nodeBase + t] = bBase + excl;
            dis[nodeBase + t] = rsqrtf(1.0f + (float)myc);
        }
    }
    if (t == 0 && b == gridDim.x - 1) offsets[N] = E;
    __syncthreads();
    for (int i = bBase + t; i < bEnd; i += 256) {
        int pk = pairs[i];
        int pos = bBase + atomicAdd(&cur[pk & 127], 1);
        csr_src[pos] = ((unsigned)pk) >> 7;
    }
}

// ================= layers =================

// register-tiled 64x64 GEMM, bf16 output PREMULTIPLIED by dis[row]:
// outb[r,c] = f2bf(dis[r] * (in @ W)[r,c]).  Row n of outb zeroed.
__global__ __launch_bounds__(256) void gemm64_k(
    const float* __restrict__ in, const float* __restrict__ W,
    const float* __restrict__ dis, unsigned short* __restrict__ outb, int n)
{
    __shared__ float HsT[HD][68];
    __shared__ float Ws[HD][HD];
    int t = threadIdx.x;
    int rowBase = blockIdx.x * 64;

    for (int i = t; i < HD * HD / 4; i += 256)
        ((float4*)Ws)[i] = ((const float4*)W)[i];

    if (blockIdx.x == 0 && t < 64)   // zero pad-row n (gather target for tails)
        outb[(size_t)n * HD + t] = 0;

    {
        int k0 = (t & 15) * 4;
        for (int it = 0; it < 4; ++it) {
            int r = (t >> 4) + it * 16;
            int row = rowBase + r;
            float4 v = make_float4(0.f, 0.f, 0.f, 0.f);
            if (row < n)
                v = *(const float4*)&in[(size_t)row * HD + k0];
            HsT[k0 + 0][r] = v.x;
            HsT[k0 + 1][r] = v.y;
            HsT[k0 + 2][r] = v.z;
            HsT[k0 + 3][r] = v.w;
        }
    }
    __syncthreads();

    int c4 = (t & 15) * 4;
    int r4 = (t >> 4) * 4;
    float acc[4][4];
    #pragma unroll
    for (int i = 0; i < 4; ++i)
        #pragma unroll
        for (int j = 0; j < 4; ++j) acc[i][j] = 0.f;

    #pragma unroll 8
    for (int k = 0; k < HD; ++k) {
        float4 a = *(const float4*)&HsT[k][r4];
        float4 b = *(const float4*)&Ws[k][c4];
        acc[0][0] += a.x * b.x; acc[0][1] += a.x * b.y; acc[0][2] += a.x * b.z; acc[0][3] += a.x * b.w;
        acc[1][0] += a.y * b.x; acc[1][1] += a.y * b.y; acc[1][2] += a.y * b.z; acc[1][3] += a.y * b.w;
        acc[2][0] += a.z * b.x; acc[2][1] += a.z * b.y; acc[2][2] += a.z * b.z; acc[2][3] += a.z * b.w;
        acc[3][0] += a.w * b.x; acc[3][1] += a.w * b.y; acc[3][2] += a.w * b.z; acc[3][3] += a.w * b.w;
    }

    #pragma unroll
    for (int i = 0; i < 4; ++i) {
        int row = rowBase + r4 + i;
        if (row < n) {
            float ds = dis[row];
            ushort4 o;
            o.x = f2bf(ds * acc[i][0]); o.y = f2bf(ds * acc[i][1]);
            o.z = f2bf(ds * acc[i][2]); o.w = f2bf(ds * acc[i][3]);
            *(ushort4*)&outb[(size_t)row * HD + c4] = o;
        }
    }
}

// ---- 4-nodes-per-wave gather core (proven; + next-block index prefetch) ----
__device__ __forceinline__ void gather4(const unsigned short* __restrict__ hwb,
    const int* __restrict__ offsets, const int* __restrict__ csr_src,
    int node, bool act, int n, int sub, int fl,
    float& a0, float& a1, float& a2, float& a3)
{
    int beg = 0, end = 0;
    if (act) { beg = offsets[node]; end = offsets[node + 1]; }
    int deg = end - beg;
    int md = deg;
    md = max(md, __shfl_xor(md, 16, 64));
    md = max(md, __shfl_xor(md, 32, 64));   // max degree over the wave's 4 nodes

    int nodeC = act ? node : n;             // inactive -> zero row
    uint2 sv = *(const uint2*)(hwb + ((size_t)nodeC << 6) + (fl << 2));
    a0 = u2f(sv.x << 16); a1 = u2f(sv.x & 0xFFFF0000u);
    a2 = u2f(sv.y << 16); a3 = u2f(sv.y & 0xFFFF0000u);

    int base = sub << 4;
    int idxv = (fl < deg) ? csr_src[beg + fl] : n;       // iteration-0 indices
    for (int jb = 0; jb < md; jb += 16) {
        int e2 = jb + 16 + fl;                           // prefetch next block
        int nidx = (e2 < deg) ? csr_src[beg + e2] : n;   // guarded, never OOB
        {
            uint2 g[8];
            #pragma unroll
            for (int j = 0; j < 8; ++j) {
                int row = __shfl(idxv, base + j, 64);
                g[j] = *(const uint2*)(hwb + ((size_t)row << 6) + (fl << 2));
            }
            #pragma unroll
            for (int j = 0; j < 8; ++j) {
                a0 += u2f(g[j].x << 16); a1 += u2f(g[j].x & 0xFFFF0000u);
                a2 += u2f(g[j].y << 16); a3 += u2f(g[j].y & 0xFFFF0000u);
            }
        }
        if (jb + 8 < md) {
            uint2 g[8];
            #pragma unroll
            for (int j = 0; j < 8; ++j) {
                int row = __shfl(idxv, base + 8 + j, 64);
                g[j] = *(const uint2*)(hwb + ((size_t)row << 6) + (fl << 2));
            }
            #pragma unroll
            for (int j = 0; j < 8; ++j) {
                a0 += u2f(g[j].x << 16); a1 += u2f(g[j].x & 0xFFFF0000u);
                a2 += u2f(g[j].y << 16); a3 += u2f(g[j].y & 0xFFFF0000u);
            }
        }
        idxv = nidx;
    }
}

// Fused {agg_l -> relu(+b) -> GEMM W_{l+1} -> *dis -> bf16 table}
__global__ __launch_bounds__(256) void agg_gemm_k(
    const unsigned short* __restrict__ hwb, const float* __restrict__ dis,
    const int* __restrict__ offsets, const int* __restrict__ csr_src,
    const float* __restrict__ b_prev, const float* __restrict__ W,
    unsigned short* __restrict__ outb, int n)
{
    __shared__ float As[16][68];
    __shared__ float Ws[HD][HD];
    int t    = threadIdx.x;
    int lane = t & 63;
    int sub  = lane >> 4;
    int fl   = lane & 15;
    int w    = t >> 6;
    int nib  = w * 4 + sub;
    int nodeBase = blockIdx.x * 16;
    int node = nodeBase + nib;
    bool act = node < n;

    for (int i = t; i < HD * HD / 4; i += 256)
        ((float4*)Ws)[i] = ((const float4*)W)[i];

    if (blockIdx.x == 0 && t < 64)   // zero pad-row n of OUTPUT table
        outb[(size_t)n * HD + t] = 0;

    float a0, a1, a2, a3;
    gather4(hwb, offsets, csr_src, node, act, n, sub, fl, a0, a1, a2, a3);

    float ds = act ? dis[node] : 0.f;
    int c0 = fl << 2;
    float4 bb = *(const float4*)&b_prev[c0];
    float4 v;
    v.x = fmaxf(a0 * ds + bb.x, 0.f);
    v.y = fmaxf(a1 * ds + bb.y, 0.f);
    v.z = fmaxf(a2 * ds + bb.z, 0.f);
    v.w = fmaxf(a3 * ds + bb.w, 0.f);
    *(float4*)&As[nib][c0] = v;
    __syncthreads();

    int r  = t & 15;
    int c4 = (t >> 4) << 2;
    float acc0 = 0.f, acc1 = 0.f, acc2 = 0.f, acc3 = 0.f;
    #pragma unroll 4
    for (int k = 0; k < HD; k += 4) {
        float4 a  = *(const float4*)&As[r][k];
        float4 w0 = *(const float4*)&Ws[k + 0][c4];
        float4 w1 = *(const float4*)&Ws[k + 1][c4];
        float4 w2 = *(const float4*)&Ws[k + 2][c4];
        float4 w3 = *(const float4*)&Ws[k + 3][c4];
        acc0 += a.x * w0.x + a.y * w1.x + a.z * w2.x + a.w * w3.x;
        acc1 += a.x * w0.y + a.y * w1.y + a.z * w2.y + a.w * w3.y;
        acc2 += a.x * w0.z + a.y * w1.z + a.z * w2.z + a.w * w3.z;
        acc3 += a.x * w0.w + a.y * w1.w + a.z * w2.w + a.w * w3.w;
    }
    int orow = nodeBase + r;
    if (orow < n) {
        float d2 = dis[orow];
        ushort4 o;
        o.x = f2bf(d2 * acc0); o.y = f2bf(d2 * acc1);
        o.z = f2bf(d2 * acc2); o.w = f2bf(d2 * acc3);
        *(ushort4*)&outb[(size_t)orow * HD + c4] = o;
    }
}

// Layer-3 agg fused with pool stage 1.  16 nodes per block; block-level
// fast path (all 16 nodes same graph -> one atomic per column).
__global__ __launch_bounds__(256) void agg_pool4_k(const unsigned short* __restrict__ hwb,
    const float* __restrict__ dis, const int* __restrict__ offsets,
    const int* __restrict__ csr_src, const int* __restrict__ batch,
    float* __restrict__ partial, int n)
{
    __shared__ float sh[16][68];
    __shared__ int gids[16];
    __shared__ int allsame;
    int t    = threadIdx.x;
    int lane = t & 63;
    int sub  = lane >> 4;
    int fl   = lane & 15;
    int w    = t >> 6;
    int nib  = w * 4 + sub;                 // node-in-block 0..15
    int node = blockIdx.x * 16 + nib;
    bool act = node < n;

    float a0, a1, a2, a3;
    gather4(hwb, offsets, csr_src, node, act, n, sub, fl, a0, a1, a2, a3);

    float ds = act ? dis[node] : 0.f;
    *(float4*)&sh[nib][fl << 2] = make_float4(a0 * ds, a1 * ds, a2 * ds, a3 * ds);
    if (fl == 0) gids[nib] = act ? batch[node] : -1;
    __syncthreads();

    if (t == 0) {
        int g0 = gids[0];
        int ok = (g0 >= 0);
        #pragma unroll
        for (int r = 1; r < 16; ++r) ok &= (gids[r] == g0);
        allsame = ok;
    }
    __syncthreads();

    int slot = blockIdx.x & (PSUB - 1);
    if (allsame) {
        if (t < 64) {
            float s = 0.f;
            #pragma unroll
            for (int r = 0; r < 16; ++r) s += sh[r][t];
            atomicAdd(&partial[((size_t)gids[0] * PSUB + slot) * HD + t], s);
        }
    } else {
        int c  = t & 63;
        int r0 = w * 4;
        int ga = gids[r0], gb = gids[r0 + 1], gc = gids[r0 + 2], gd = gids[r0 + 3];
        if (ga == gb && gb == gc && gc == gd && ga >= 0) {
            float v = sh[r0][c] + sh[r0 + 1][c] + sh[r0 + 2][c] + sh[r0 + 3][c];
            atomicAdd(&partial[((size_t)ga * PSUB + slot) * HD + c], v);
        } else {
            if (ga >= 0) atomicAdd(&partial[((size_t)ga * PSUB + slot) * HD + c], sh[r0][c]);
            if (gb >= 0) atomicAdd(&partial[((size_t)gb * PSUB + slot) * HD + c], sh[r0 + 1][c]);
            if (gc >= 0) atomicAdd(&partial[((size_t)gc * PSUB + slot) * HD + c], sh[r0 + 2][c]);
            if (gd >= 0) atomicAdd(&partial[((size_t)gd * PSUB + slot) * HD + c], sh[r0 + 3][c]);
        }
    }
}

// pooling stage 2: reduce partials, mean + b3, final linear
__global__ __launch_bounds__(64) void pool2_k(const float* __restrict__ partial,
    const int* __restrict__ gstart, const float* __restrict__ b3,
    const float* __restrict__ Wl, const float* __restrict__ bl,
    float* __restrict__ out, int O)
{
    __shared__ float pooled[HD];
    int g = blockIdx.x;
    int t = threadIdx.x;
    float sum = 0.0f;
    #pragma unroll
    for (int s = 0; s < PSUB; ++s)
        sum += partial[((size_t)g * PSUB + s) * HD + t];
    float cnt = (float)(gstart[g + 1] - gstart[g]);
    pooled[t] = sum / cnt + b3[t];
    __syncthreads();
    if (t < O) {
        float acc = bl[t];
        #pragma unroll
        for (int k = 0; k < HD; ++k) acc += pooled[k] * Wl[k * O + t];
        out[g * O + t] = acc;
    }
}

extern "C" void kernel_launch(void* const* d_in, const int* in_sizes, int n_in,
                              void* d_out, int out_size, void* d_ws, size_t ws_size,
                              hipStream_t stream)
{
    const float* x    = (const float*)d_in[0];
    const int*   ei   = (const int*)d_in[1];
    const int*   batch= (const int*)d_in[2];
    const float* W1   = (const float*)d_in[3];
    const float* b1   = (const float*)d_in[4];
    const float* W2   = (const float*)d_in[5];
    const float* b2   = (const float*)d_in[6];
    const float* W3   = (const float*)d_in[7];
    const float* b3   = (const float*)d_in[8];
    const float* Wl   = (const float*)d_in[9];
    const float* bl   = (const float*)d_in[10];
    float* out = (float*)d_out;

    const int N = in_sizes[0] / HD;
    const int E = in_sizes[1] / 2;
    const int O = in_sizes[10];
    const int G = out_size / O;

    const int* src = ei;
    const int* dst = ei + E;

    // ---- workspace layout (256 B aligned) ----
    char* p = (char*)d_ws;
    auto take = [&](size_t bytes) { char* r = p; p += (bytes + 255) & ~(size_t)255; return r; };
    int*   csr_src = (int*)  take((size_t)(E + 256) * 4);  // padded for over-read
    int*   offsets = (int*)  take((size_t)(N + 1) * 4);
    float* dis     = (float*)take((size_t)N * 4);
    int*   gstart  = (int*)  take((size_t)(G + 1) * 4);
    float* partial = (float*)take((size_t)G * PSUB * HD * 4);           // 256 KB
    unsigned short* hwb  = (unsigned short*)take((size_t)(N + 1) * HD * 2);  // 6.4 MB (+zero row)
    unsigned short* hwb2 = (unsigned short*)take((size_t)(N + 1) * HD * 2);  // 6.4 MB (+zero row)

    // aliases into regions not yet live during CSR build:
    int* pairs   = (int*)hwb;                  // E*4 = 3.2 MB (packed)
    int* hist    = (int*)hwb2;                 // NBKT*NBLK*4 = 512 KB (bucket-major)
    int* bucketb = hist + NBKT * NBLK;         // (NBKT+1)*4

    const int TB = 256;
    int chunk   = (E + NBLK - 1) / NBLK;
    int nb_gemm = (N + 63) / 64;
    int nb_agg4 = (N + 15) / 16;               // 16 nodes per block (4/wave)
    int nbuck   = (N + 127) / 128;
    int psz     = G * PSUB * HD;

    // ---- CSR build: 3 kernels ----
    hist1_k<<<NBLK, TB, 0, stream>>>(dst, hist, E, chunk, partial, psz,
                                     batch, gstart, N, G);
    append2_k<<<NBLK, TB, 0, stream>>>(src, dst, hist, pairs, bucketb, E, chunk);
    bucket_csr_k<<<nbuck, TB, 0, stream>>>(pairs, bucketb, offsets, dis, csr_src, N, E);

    // ---- layer 1: x @ W1 -> dis-premult bf16 table ----
    gemm64_k<<<nb_gemm, TB, 0, stream>>>(x, W1, dis, hwb, N);

    // ---- layer 2 fused: agg(hwb) -> relu(+b1) -> @W2 -> hwb2 ----
    agg_gemm_k<<<nb_agg4, TB, 0, stream>>>(hwb, dis, offsets, csr_src, b1, W2, hwb2, N);

    // ---- layer 3 fused: agg(hwb2) -> relu(+b2) -> @W3 -> hwb ----
    agg_gemm_k<<<nb_agg4, TB, 0, stream>>>(hwb2, dis, offsets, csr_src, b2, W3, hwb, N);

    // ---- final agg fused with pool stage 1 ----
    agg_pool4_k<<<nb_agg4, TB, 0, stream>>>(hwb, dis, offsets, csr_src, batch, partial, N);

    // ---- pool stage 2 + final linear ----
    pool2_k<<<G, 64, 0, stream>>>(partial, gstart, b3, Wl, bl, out, O);
}

// Round 8
// 184.868 us; speedup vs baseline: 1.0677x; 1.0677x over previous
//
#include <hip/hip_runtime.h>

#define HD 64      // hidden/feature dim (D == H == 64)
#define PSUB 16    // partial slots per graph (pool accumulation spread)
#define NBLK 256   // histogram blocks (edge slices)
#define LOG_NBLK 8
#define NBKT 512   // dst buckets (bucket = dst >> 7, 128 nodes each; N <= 65536)

// ---- bf16 helpers (manual, RNE) ----
__device__ __forceinline__ unsigned short f2bf(float f) {
    union { float f; unsigned u; } v; v.f = f;
    unsigned r = v.u + 0x7FFF + ((v.u >> 16) & 1);
    return (unsigned short)(r >> 16);
}
__device__ __forceinline__ float u2f(unsigned u) {
    union { unsigned u; float f; } v; v.u = u;
    return v.f;
}

// ================= atomic-free bucketed CSR build (verified R4/R6 chain) =================

// also zeroes the pool 'partial' buffer (grid-parallel)
__global__ __launch_bounds__(256) void hist1_k(const int* __restrict__ dst,
                                               int* __restrict__ hist, int E, int chunk,
                                               float* __restrict__ partial, int psz)
{
    __shared__ int lh[NBKT];
    int t = threadIdx.x;
    for (int i = t; i < NBKT; i += 256) lh[i] = 0;
    for (int i = blockIdx.x * 256 + t; i < psz; i += gridDim.x * 256)
        partial[i] = 0.f;
    __syncthreads();
    int base = blockIdx.x * chunk;
    int end  = min(base + chunk, E);
    for (int i = base + t; i < end; i += 256)
        atomicAdd(&lh[dst[i] >> 7], 1);
    __syncthreads();
    for (int i = t; i < NBKT; i += 256)
        hist[blockIdx.x * NBKT + i] = lh[i];
}

__global__ __launch_bounds__(256) void scanA_k(const int* __restrict__ hist,
                                               int* __restrict__ tsum)
{
    __shared__ int s[256];
    int t = threadIdx.x;
    int l = blockIdx.x * 256 + t;
    int phys = (l & (NBLK - 1)) * NBKT + (l >> LOG_NBLK);
    s[t] = hist[phys];
    __syncthreads();
    for (int off = 128; off > 0; off >>= 1) {
        if (t < off) s[t] += s[t + off];
        __syncthreads();
    }
    if (t == 0) tsum[blockIdx.x] = s[0];
}

__global__ __launch_bounds__(1024) void scanB_k(int* __restrict__ tsum, int nb,
    const int* __restrict__ batch, int* __restrict__ gstart, int n, int G)
{
    __shared__ int s[1024];
    int t = threadIdx.x;
    int v = (t < nb) ? tsum[t] : 0;
    s[t] = v;
    __syncthreads();
    for (int off = 1; off < 1024; off <<= 1) {
        int u = (t >= off) ? s[t - off] : 0;
        __syncthreads();
        s[t] += u;
        __syncthreads();
    }
    if (t < nb) tsum[t] = s[t] - v;
    if (t <= G) {
        if (t == G) gstart[t] = n;
        else {
            int lo = 0, hi = n;
            while (lo < hi) { int m = (lo + hi) >> 1; if (batch[m] < t) lo = m + 1; else hi = m; }
            gstart[t] = lo;
        }
    }
}

__global__ __launch_bounds__(256) void scanC_k(const int* __restrict__ hist,
                                               const int* __restrict__ tsum,
                                               int* __restrict__ scanned)
{
    __shared__ int s[256];
    int t = threadIdx.x;
    int l = blockIdx.x * 256 + t;
    int phys = (l & (NBLK - 1)) * NBKT + (l >> LOG_NBLK);
    int own = hist[phys];
    s[t] = own;
    __syncthreads();
    for (int off = 1; off < 256; off <<= 1) {
        int u = (t >= off) ? s[t - off] : 0;
        __syncthreads();
        s[t] += u;
        __syncthreads();
    }
    scanned[l] = tsum[blockIdx.x] + s[t] - own;
}

__global__ __launch_bounds__(256) void append_k(const int* __restrict__ src,
    const int* __restrict__ dst, const int* __restrict__ scanned,
    int* __restrict__ pairs, int E, int chunk)
{
    __shared__ int cur[NBKT];
    int t = threadIdx.x;
    int blk = blockIdx.x;
    for (int i = t; i < NBKT; i += 256) cur[i] = scanned[i * NBLK + blk];
    __syncthreads();
    int base = blk * chunk;
    int end  = min(base + chunk, E);
    for (int i = base + t; i < end; i += 256) {
        int s = src[i], d = dst[i];
        int p = atomicAdd(&cur[d >> 7], 1);
        pairs[p] = (s << 7) | (d & 127);
    }
}

__global__ __launch_bounds__(256) void bucket_csr_k(const int* __restrict__ pairs,
    const int* __restrict__ scanned, int* __restrict__ offsets,
    float* __restrict__ dis, int* __restrict__ csr_src, int N, int E)
{
    __shared__ int cnt[128];
    __shared__ int sc[128];
    __shared__ int cur[128];
    int t = threadIdx.x;
    int b = blockIdx.x;
    int nodeBase = b * 128;
    int nNodes = min(128, N - nodeBase);
    int bBase = scanned[b * NBLK];
    int bEnd  = (b + 1 < NBKT) ? scanned[(b + 1) * NBLK] : E;

    if (t < 128) cnt[t] = 0;
    __syncthreads();
    for (int i = bBase + t; i < bEnd; i += 256)
        atomicAdd(&cnt[pairs[i] & 127], 1);
    __syncthreads();
    int myc = (t < 128) ? cnt[t] : 0;
    if (t < 128) sc[t] = myc;
    __syncthreads();
    for (int off = 1; off < 128; off <<= 1) {
        int u = (t < 128 && t >= off) ? sc[t - off] : 0;
        __syncthreads();
        if (t < 128) sc[t] += u;
        __syncthreads();
    }
    if (t < 128) {
        int excl = sc[t] - myc;
        cur[t] = excl;
        if (t < nNodes) {
            offsets[nodeBase + t] = bBase + excl;
            dis[nodeBase + t] = rsqrtf(1.0f + (float)myc);
        }
    }
    if (t == 0 && b == gridDim.x - 1) offsets[N] = E;
    __syncthreads();
    for (int i = bBase + t; i < bEnd; i += 256) {
        int pk = pairs[i];
        int pos = bBase + atomicAdd(&cur[pk & 127], 1);
        csr_src[pos] = ((unsigned)pk) >> 7;
    }
}

// ================= layers =================

// register-tiled 64x64 GEMM, bf16 output PREMULTIPLIED by dis[row]  (verified)
__global__ __launch_bounds__(256) void gemm64_k(
    const float* __restrict__ in, const float* __restrict__ W,
    const float* __restrict__ dis, unsigned short* __restrict__ outb, int n)
{
    __shared__ float HsT[HD][68];
    __shared__ float Ws[HD][HD];
    int t = threadIdx.x;
    int rowBase = blockIdx.x * 64;

    for (int i = t; i < HD * HD / 4; i += 256)
        ((float4*)Ws)[i] = ((const float4*)W)[i];

    if (blockIdx.x == 0 && t < 64)   // zero pad-row n (gather target for tails)
        outb[(size_t)n * HD + t] = 0;

    {
        int k0 = (t & 15) * 4;
        for (int it = 0; it < 4; ++it) {
            int r = (t >> 4) + it * 16;
            int row = rowBase + r;
            float4 v = make_float4(0.f, 0.f, 0.f, 0.f);
            if (row < n)
                v = *(const float4*)&in[(size_t)row * HD + k0];
            HsT[k0 + 0][r] = v.x;
            HsT[k0 + 1][r] = v.y;
            HsT[k0 + 2][r] = v.z;
            HsT[k0 + 3][r] = v.w;
        }
    }
    __syncthreads();

    int c4 = (t & 15) * 4;
    int r4 = (t >> 4) * 4;
    float acc[4][4];
    #pragma unroll
    for (int i = 0; i < 4; ++i)
        #pragma unroll
        for (int j = 0; j < 4; ++j) acc[i][j] = 0.f;

    #pragma unroll 8
    for (int k = 0; k < HD; ++k) {
        float4 a = *(const float4*)&HsT[k][r4];
        float4 b = *(const float4*)&Ws[k][c4];
        acc[0][0] += a.x * b.x; acc[0][1] += a.x * b.y; acc[0][2] += a.x * b.z; acc[0][3] += a.x * b.w;
        acc[1][0] += a.y * b.x; acc[1][1] += a.y * b.y; acc[1][2] += a.y * b.z; acc[1][3] += a.y * b.w;
        acc[2][0] += a.z * b.x; acc[2][1] += a.z * b.y; acc[2][2] += a.z * b.z; acc[2][3] += a.z * b.w;
        acc[3][0] += a.w * b.x; acc[3][1] += a.w * b.y; acc[3][2] += a.w * b.z; acc[3][3] += a.w * b.w;
    }

    #pragma unroll
    for (int i = 0; i < 4; ++i) {
        int row = rowBase + r4 + i;
        if (row < n) {
            float ds = dis[row];
            ushort4 o;
            o.x = f2bf(ds * acc[i][0]); o.y = f2bf(ds * acc[i][1]);
            o.z = f2bf(ds * acc[i][2]); o.w = f2bf(ds * acc[i][3]);
            *(ushort4*)&outb[(size_t)row * HD + c4] = o;
        }
    }
}

// ---- 8-nodes-per-wave gather core: uint4 (16B) per lane, 8 lanes per node.
// One gather instruction fetches 8 full 128-B rows -> 64 rows in flight per
// wave with g[8] (2x the uint2 core) at ~+16 VGPR.  Lane owns 8 cols.
__device__ __forceinline__ void gather8(const unsigned short* __restrict__ hwb,
    const int* __restrict__ offsets, const int* __restrict__ csr_src,
    int node, bool act, int n, int fl, float* a /*a[8]*/)
{
    int beg = 0, end = 0;
    if (act) { beg = offsets[node]; end = offsets[node + 1]; }
    int deg = end - beg;
    int md = deg;
    md = max(md, __shfl_xor(md, 8, 64));
    md = max(md, __shfl_xor(md, 16, 64));
    md = max(md, __shfl_xor(md, 32, 64));   // max degree over the wave's 8 nodes

    int nodeC = act ? node : n;             // inactive -> zero row
    uint4 sv = *(const uint4*)(hwb + ((size_t)nodeC << 6) + (fl << 3));
    a[0] = u2f(sv.x << 16); a[1] = u2f(sv.x & 0xFFFF0000u);
    a[2] = u2f(sv.y << 16); a[3] = u2f(sv.y & 0xFFFF0000u);
    a[4] = u2f(sv.z << 16); a[5] = u2f(sv.z & 0xFFFF0000u);
    a[6] = u2f(sv.w << 16); a[7] = u2f(sv.w & 0xFFFF0000u);

    int grpbase = threadIdx.x & 56;         // lane & ~7 (within wave: lane&56)
    int idxv = (fl < deg) ? csr_src[beg + fl] : n;     // iter-0: 8 edges/node
    for (int jb = 0; jb < md; jb += 8) {
        int e2 = jb + 8 + fl;                          // prefetch next iter
        int nidx = (e2 < deg) ? csr_src[beg + e2] : n;
        uint4 g[8];
        #pragma unroll
        for (int j = 0; j < 8; ++j) {
            int row = __shfl(idxv, grpbase + j, 64);
            g[j] = *(const uint4*)(hwb + ((size_t)row << 6) + (fl << 3));
        }
        #pragma unroll
        for (int j = 0; j < 8; ++j) {
            a[0] += u2f(g[j].x << 16); a[1] += u2f(g[j].x & 0xFFFF0000u);
            a[2] += u2f(g[j].y << 16); a[3] += u2f(g[j].y & 0xFFFF0000u);
            a[4] += u2f(g[j].z << 16); a[5] += u2f(g[j].z & 0xFFFF0000u);
            a[6] += u2f(g[j].w << 16); a[7] += u2f(g[j].w & 0xFFFF0000u);
        }
        idxv = nidx;
    }
}

// Fused {agg_l -> relu(+b) -> GEMM W_{l+1} -> *dis -> bf16 table}.
// Block = 256 threads = 4 waves = 32 nodes.
__global__ __launch_bounds__(256) void agg_gemm_k(
    const unsigned short* __restrict__ hwb, const float* __restrict__ dis,
    const int* __restrict__ offsets, const int* __restrict__ csr_src,
    const float* __restrict__ b_prev, const float* __restrict__ W,
    unsigned short* __restrict__ outb, int n)
{
    __shared__ float As[32][68];
    __shared__ float Ws[HD][HD];
    int t    = threadIdx.x;
    int lane = t & 63;
    int grp  = lane >> 3;                  // node group 0..7
    int fl   = lane & 7;                   // lane within group
    int w    = t >> 6;
    int nib  = w * 8 + grp;                // node-in-block 0..31
    int nodeBase = blockIdx.x * 32;
    int node = nodeBase + nib;
    bool act = node < n;

    for (int i = t; i < HD * HD / 4; i += 256)
        ((float4*)Ws)[i] = ((const float4*)W)[i];

    if (blockIdx.x == 0 && t < 64)   // zero pad-row n of OUTPUT table
        outb[(size_t)n * HD + t] = 0;

    float a[8];
    gather8(hwb, offsets, csr_src, node, act, n, fl, a);

    float ds = act ? dis[node] : 0.f;
    int c0 = fl << 3;
    float4 b0 = *(const float4*)&b_prev[c0];
    float4 b1 = *(const float4*)&b_prev[c0 + 4];
    float4 v0, v1;
    v0.x = fmaxf(a[0] * ds + b0.x, 0.f); v0.y = fmaxf(a[1] * ds + b0.y, 0.f);
    v0.z = fmaxf(a[2] * ds + b0.z, 0.f); v0.w = fmaxf(a[3] * ds + b0.w, 0.f);
    v1.x = fmaxf(a[4] * ds + b1.x, 0.f); v1.y = fmaxf(a[5] * ds + b1.y, 0.f);
    v1.z = fmaxf(a[6] * ds + b1.z, 0.f); v1.w = fmaxf(a[7] * ds + b1.w, 0.f);
    *(float4*)&As[nib][c0]     = v0;
    *(float4*)&As[nib][c0 + 4] = v1;
    __syncthreads();

    // GEMM: 32 rows x 64 cols; thread -> (r = t&31, cols c8 = (t>>5)*8)
    int r  = t & 31;
    int c8 = (t >> 5) << 3;
    float s0 = 0.f, s1 = 0.f, s2 = 0.f, s3 = 0.f, s4 = 0.f, s5 = 0.f, s6 = 0.f, s7 = 0.f;
    #pragma unroll 4
    for (int k = 0; k < HD; k += 4) {
        float4 aa = *(const float4*)&As[r][k];
        #pragma unroll
        for (int kk = 0; kk < 4; ++kk) {
            float av = (kk == 0) ? aa.x : (kk == 1) ? aa.y : (kk == 2) ? aa.z : aa.w;
            float4 w0 = *(const float4*)&Ws[k + kk][c8];
            float4 w1 = *(const float4*)&Ws[k + kk][c8 + 4];
            s0 += av * w0.x; s1 += av * w0.y; s2 += av * w0.z; s3 += av * w0.w;
            s4 += av * w1.x; s5 += av * w1.y; s6 += av * w1.z; s7 += av * w1.w;
        }
    }
    int orow = nodeBase + r;
    if (orow < n) {
        float d2 = dis[orow];
        ushort4 o0, o1;
        o0.x = f2bf(d2 * s0); o0.y = f2bf(d2 * s1); o0.z = f2bf(d2 * s2); o0.w = f2bf(d2 * s3);
        o1.x = f2bf(d2 * s4); o1.y = f2bf(d2 * s5); o1.z = f2bf(d2 * s6); o1.w = f2bf(d2 * s7);
        *(ushort4*)&outb[(size_t)orow * HD + c8]     = o0;
        *(ushort4*)&outb[(size_t)orow * HD + c8 + 4] = o1;
    }
}

// Layer-3 agg fused with pool stage 1.  32 nodes per block.
__global__ __launch_bounds__(256) void agg_pool8_k(const unsigned short* __restrict__ hwb,
    const float* __restrict__ dis, const int* __restrict__ offsets,
    const int* __restrict__ csr_src, const int* __restrict__ batch,
    float* __restrict__ partial, int n)
{
    __shared__ float sh[32][68];
    __shared__ int gids[32];
    __shared__ int allsame;
    int t    = threadIdx.x;
    int lane = t & 63;
    int grp  = lane >> 3;
    int fl   = lane & 7;
    int w    = t >> 6;
    int nib  = w * 8 + grp;                 // node-in-block 0..31
    int node = blockIdx.x * 32 + nib;
    bool act = node < n;

    float a[8];
    gather8(hwb, offsets, csr_src, node, act, n, fl, a);

    float ds = act ? dis[node] : 0.f;
    int c0 = fl << 3;
    *(float4*)&sh[nib][c0]     = make_float4(a[0] * ds, a[1] * ds, a[2] * ds, a[3] * ds);
    *(float4*)&sh[nib][c0 + 4] = make_float4(a[4] * ds, a[5] * ds, a[6] * ds, a[7] * ds);
    if (fl == 0) gids[nib] = act ? batch[node] : -1;
    __syncthreads();

    if (t == 0) {
        int g0 = gids[0];
        int ok = (g0 >= 0);
        #pragma unroll
        for (int r = 1; r < 32; ++r) ok &= (gids[r] == g0);
        allsame = ok;
    }
    __syncthreads();

    int slot = blockIdx.x & (PSUB - 1);
    if (allsame) {
        if (t < 64) {
            float s = 0.f;
            #pragma unroll
            for (int r = 0; r < 32; ++r) s += sh[r][t];
            atomicAdd(&partial[((size_t)gids[0] * PSUB + slot) * HD + t], s);
        }
    } else {
        int c  = lane;                      // 0..63
        int r0 = w * 8;                     // this wave's 8 nodes
        int gw = gids[r0];
        bool same8 = (gw >= 0);
        #pragma unroll
        for (int rr = 1; rr < 8; ++rr) same8 &= (gids[r0 + rr] == gw);
        if (same8) {
            float v = 0.f;
            #pragma unroll
            for (int rr = 0; rr < 8; ++rr) v += sh[r0 + rr][c];
            atomicAdd(&partial[((size_t)gw * PSUB + slot) * HD + c], v);
        } else {
            #pragma unroll
            for (int rr = 0; rr < 8; ++rr) {
                int gg = gids[r0 + rr];
                if (gg >= 0)
                    atomicAdd(&partial[((size_t)gg * PSUB + slot) * HD + c], sh[r0 + rr][c]);
            }
        }
    }
}

// pooling stage 2: reduce partials, mean + b3, final linear
__global__ __launch_bounds__(64) void pool2_k(const float* __restrict__ partial,
    const int* __restrict__ gstart, const float* __restrict__ b3,
    const float* __restrict__ Wl, const float* __restrict__ bl,
    float* __restrict__ out, int O)
{
    __shared__ float pooled[HD];
    int g = blockIdx.x;
    int t = threadIdx.x;
    float sum = 0.0f;
    #pragma unroll
    for (int s = 0; s < PSUB; ++s)
        sum += partial[((size_t)g * PSUB + s) * HD + t];
    float cnt = (float)(gstart[g + 1] - gstart[g]);
    pooled[t] = sum / cnt + b3[t];
    __syncthreads();
    if (t < O) {
        float acc = bl[t];
        #pragma unroll
        for (int k = 0; k < HD; ++k) acc += pooled[k] * Wl[k * O + t];
        out[g * O + t] = acc;
    }
}

extern "C" void kernel_launch(void* const* d_in, const int* in_sizes, int n_in,
                              void* d_out, int out_size, void* d_ws, size_t ws_size,
                              hipStream_t stream)
{
    const float* x    = (const float*)d_in[0];
    const int*   ei   = (const int*)d_in[1];
    const int*   batch= (const int*)d_in[2];
    const float* W1   = (const float*)d_in[3];
    const float* b1   = (const float*)d_in[4];
    const float* W2   = (const float*)d_in[5];
    const float* b2   = (const float*)d_in[6];
    const float* W3   = (const float*)d_in[7];
    const float* b3   = (const float*)d_in[8];
    const float* Wl   = (const float*)d_in[9];
    const float* bl   = (const float*)d_in[10];
    float* out = (float*)d_out;

    const int N = in_sizes[0] / HD;
    const int E = in_sizes[1] / 2;
    const int O = in_sizes[10];
    const int G = out_size / O;

    const int* src = ei;
    const int* dst = ei + E;

    // ---- workspace layout (256 B aligned) ----
    char* p = (char*)d_ws;
    auto take = [&](size_t bytes) { char* r = p; p += (bytes + 255) & ~(size_t)255; return r; };
    int*   csr_src = (int*)  take((size_t)(E + 256) * 4);  // padded for over-read
    int*   offsets = (int*)  take((size_t)(N + 1) * 4);
    float* dis     = (float*)take((size_t)N * 4);
    int*   gstart  = (int*)  take((size_t)(G + 1) * 4);
    float* partial = (float*)take((size_t)G * PSUB * HD * 4);           // 256 KB
    unsigned short* hwb  = (unsigned short*)take((size_t)(N + 1) * HD * 2);  // 6.4 MB (+zero row)
    unsigned short* hwb2 = (unsigned short*)take((size_t)(N + 1) * HD * 2);  // 6.4 MB (+zero row)

    // aliases into regions not yet live during CSR build:
    int* pairs   = (int*)hwb;                  // E*4 = 3.2 MB (packed)
    int* hist    = (int*)hwb2;                 // NBLK*NBKT*4 = 512 KB
    int* scanned = hist + NBLK * NBKT;         // 512 KB
    int* tsum    = scanned + NBLK * NBKT;      // 2 KB

    const int TB = 256;
    int chunk   = (E + NBLK - 1) / NBLK;
    int ntiles  = (NBLK * NBKT) / 256;         // 512
    int nb_gemm = (N + 63) / 64;
    int nb_agg8 = (N + 31) / 32;               // 32 nodes per block (8/wave)
    int nbuck   = (N + 127) / 128;
    int psz     = G * PSUB * HD;

    // ---- CSR build (atomic-free counting sort, packed pairs) ----
    hist1_k<<<NBLK, TB, 0, stream>>>(dst, hist, E, chunk, partial, psz);
    scanA_k<<<ntiles, TB, 0, stream>>>(hist, tsum);
    scanB_k<<<1, 1024, 0, stream>>>(tsum, ntiles, batch, gstart, N, G);
    scanC_k<<<ntiles, TB, 0, stream>>>(hist, tsum, scanned);
    append_k<<<NBLK, TB, 0, stream>>>(src, dst, scanned, pairs, E, chunk);
    bucket_csr_k<<<nbuck, TB, 0, stream>>>(pairs, scanned, offsets, dis, csr_src, N, E);

    // ---- layer 1: x @ W1 -> dis-premult bf16 table ----
    gemm64_k<<<nb_gemm, TB, 0, stream>>>(x, W1, dis, hwb, N);

    // ---- layer 2 fused: agg(hwb) -> relu(+b1) -> @W2 -> hwb2 ----
    agg_gemm_k<<<nb_agg8, TB, 0, stream>>>(hwb, dis, offsets, csr_src, b1, W2, hwb2, N);

    // ---- layer 3 fused: agg(hwb2) -> relu(+b2) -> @W3 -> hwb ----
    agg_gemm_k<<<nb_agg8, TB, 0, stream>>>(hwb2, dis, offsets, csr_src, b2, W3, hwb, N);

    // ---- final agg fused with pool stage 1 ----
    agg_pool8_k<<<nb_agg8, TB, 0, stream>>>(hwb, dis, offsets, csr_src, batch, partial, N);

    // ---- pool stage 2 + final linear ----
    pool2_k<<<G, 64, 0, stream>>>(partial, gstart, b3, Wl, bl, out, O);
}